// Round 9
// baseline (1001.816 us; speedup 1.0000x reference)
//
#include <hip/hip_runtime.h>
#include <math.h>

#define NN 20000
#define NE 320000

typedef const float* fp;
typedef short short8 __attribute__((ext_vector_type(8)));
typedef float f32x4 __attribute__((ext_vector_type(4)));

__device__ __forceinline__ short F2B(float f) {
    unsigned u = __float_as_uint(f);
    return (short)((u + 0x7fffu + ((u >> 16) & 1u)) >> 16);
}
__device__ __forceinline__ short F2Bf(float f) {
    return (short)((__float_as_uint(f) + 0x8000u) >> 16);
}
__device__ __forceinline__ float B2F(short s) {
    return __uint_as_float(((unsigned)(unsigned short)s) << 16);
}
__device__ __forceinline__ float siluf(float v) { return v / (1.f + __expf(-v)); }

// wb layout (shorts): 0 e1hh[128][256] | 32768 Wc | 65536 e2W | 81920 c1W
// 98304 c2W[16][128] | 100352 n1W | 133120 n2W | end 149504
__global__ void k_prep_w(fp e1W, fp e2W, fp c1W, fp c2W, fp n1W, fp n2W,
                         short* __restrict__ wb) {
    int i = blockIdx.x * 256 + threadIdx.x;
    if (i >= 149504) return;
    if (i >= 32768 && i < 65536) return;
    float v;
    if (i < 32768)       { int o = i >> 8, k = i & 255; v = e1W[o * 384 + k]; }
    else if (i < 81920)  v = e2W[i - 65536];
    else if (i < 98304)  v = c1W[i - 81920];
    else if (i < 100352) { int q = i - 98304; v = (q < 1792) ? c2W[q] : 0.f; }
    else if (i < 133120) v = n1W[i - 100352];
    else                 v = n2W[i - 133120];
    wb[i] = F2B(v);
}

__global__ void k_fold(fp e1W, fp rW, fp rB, short* __restrict__ wb,
                       float* __restrict__ bc) {
    int o = blockIdx.x, k = threadIdx.x;
    float acc = 0.f;
    for (int m = 0; m < 128; m++) acc += e1W[o * 384 + 256 + m] * rW[m * 256 + k];
    wb[32768 + o * 256 + k] = F2B(acc);
    if (k == 0) {
        float b = 0.f;
        for (int m = 0; m < 128; m++) b += e1W[o * 384 + 256 + m] * rB[m];
        bc[o] = b;
    }
}

__global__ void k_prep_h(fp h, short* __restrict__ hb) {
    int i = blockIdx.x * 256 + threadIdx.x;
    if (i < NN * 128) hb[i] = F2B(h[i]);
}

__global__ void k_prep_attrT(fp attr, short* __restrict__ aT) {
    int i = blockIdx.x * 256 + threadIdx.x;
    if (i >= NN * 256) return;
    int n = i >> 8, rem = i & 255, c = rem >> 4, a = rem & 15;
    float v = (c < 14) ? attr[(size_t)n * 224 + c * 16 + a] : 0.f;
    aT[(size_t)n * 256 + a * 16 + c] = F2B(v);
}

__global__ void k_node_pre(fp x, fp cw, float* __restrict__ csum, float* __restrict__ pool) {
    int n = blockIdx.x * blockDim.x + threadIdx.x;
    if (n >= NN) return;
    float cnt = 0.f, px = 0.f, py = 0.f, pz = 0.f;
#pragma unroll
    for (int c = 0; c < 14; c++) {
        float w = cw[n * 14 + c];
        if (w != 0.f) {
            cnt += 1.f;
            px += x[(n * 14 + c) * 3 + 0];
            py += x[(n * 14 + c) * 3 + 1];
            pz += x[(n * 14 + c) * 3 + 2];
        }
    }
    if (cnt < 1.f) cnt = 1.f;
    csum[n] = cnt;
    pool[n * 3 + 0] = px / cnt;
    pool[n * 3 + 1] = py / cnt;
    pool[n * 3 + 2] = pz / cnt;
}

// ---------------- CSR build (every launch; row/col are inputs) ---------------
__global__ void k_deg(const int* __restrict__ row, const int* __restrict__ col,
                      int* __restrict__ degr, int* __restrict__ degc) {
    int e = blockIdx.x * 256 + threadIdx.x;
    if (e >= NE) return;
    atomicAdd(&degr[row[e]], 1);
    atomicAdd(&degc[col[e]], 1);
}

__global__ void k_scan(const int* __restrict__ degc, const int* __restrict__ degr,
                       int* __restrict__ offc, int* __restrict__ offr,
                       int* __restrict__ curc, int* __restrict__ curr) {
    __shared__ int part[256];
    const int t = threadIdx.x;
    const int CH = (NN + 255) / 256;
    for (int a = 0; a < 2; a++) {
        const int* deg = a ? degr : degc;
        int* off = a ? offr : offc;
        int* cur = a ? curr : curc;
        int base = t * CH;
        int s = 0;
        for (int k = 0; k < CH; k++) { int idx = base + k; if (idx < NN) s += deg[idx]; }
        part[t] = s;
        __syncthreads();
        for (int d = 1; d < 256; d <<= 1) {
            int v = (t >= d) ? part[t - d] : 0;
            __syncthreads();
            part[t] += v;
            __syncthreads();
        }
        int run = (t == 0) ? 0 : part[t - 1];
        for (int k = 0; k < CH; k++) {
            int idx = base + k;
            if (idx < NN) { off[idx] = run; cur[idx] = run; run += deg[idx]; }
        }
        if (t == 255) off[NN] = run;
        __syncthreads();
    }
}

__global__ void k_fill(const int* __restrict__ row, const int* __restrict__ col,
                       int* __restrict__ curr, int* __restrict__ curc,
                       int* __restrict__ listr, int* __restrict__ listc) {
    int e = blockIdx.x * 256 + threadIdx.x;
    if (e >= NE) return;
    int pr = atomicAdd(&curr[row[e]], 1); listr[pr] = e;
    int pc = atomicAdd(&curc[col[e]], 1); listc[pc] = e;
}

__device__ __forceinline__ void gemm_lds(const short* __restrict__ A, int sA,
                                         const short* __restrict__ W, int Ws, int K,
                                         int mt, int nt0, int nts, f32x4* acc) {
    const int lane = threadIdx.x & 63;
    const short* ap = A + (mt * 16 + (lane & 15)) * sA + ((lane >> 4) * 8);
    for (int k0 = 0; k0 < K; k0 += 32) {
        short8 a = *(const short8*)(ap + k0);
#pragma unroll
        for (int t = 0; t < nts; t++) {
            short8 b = *(const short8*)(W + ((nt0 + t) * 16 + (lane & 15)) * Ws + k0 + ((lane >> 4) * 8));
            acc[t] = __builtin_amdgcn_mfma_f32_16x16x32_bf16(a, b, acc[t], 0, 0, 0);
        }
    }
}
__device__ __forceinline__ void gemm_grow(const short* __restrict__ arow,
                                          const short* __restrict__ W, int Ws, int K,
                                          int nt0, int nts, f32x4* acc) {
    const int lane = threadIdx.x & 63;
    for (int k0 = 0; k0 < K; k0 += 32) {
        short8 a = *(const short8*)(arow + k0);
#pragma unroll
        for (int t = 0; t < nts; t++) {
            short8 b = *(const short8*)(W + ((nt0 + t) * 16 + (lane & 15)) * Ws + k0 + ((lane >> 4) * 8));
            acc[t] = __builtin_amdgcn_mfma_f32_16x16x32_bf16(a, b, acc[t], 0, 0, 0);
        }
    }
}

// ---------------- H12: per-node h@W1 | h@W2 ----------------------------------
__global__ __launch_bounds__(256, 2) void k_hw(const short* __restrict__ hb,
                                               const short* __restrict__ wb,
                                               short* __restrict__ H12) {
    __shared__ __attribute__((aligned(16))) short A[32 * 136];
    const int tid = threadIdx.x, lane = tid & 63, w = tid >> 6;
    const int bb = lane & 15, quad = lane >> 4;
    const int mt = w & 1, nh = w >> 1, nb0 = blockIdx.x * 32;
    for (int p = tid; p < 512; p += 256) {
        int i = p >> 4, v = p & 15;
        *(short8*)(A + i * 136 + v * 8) = *(const short8*)(hb + (size_t)(nb0 + i) * 128 + v * 8);
    }
    __syncthreads();
    f32x4 acc[4];
#pragma unroll
    for (int t = 0; t < 4; t++) acc[t] = (f32x4){0.f, 0.f, 0.f, 0.f};
    gemm_lds(A, 136, wb, 256, 128, mt, nh * 4, 4, acc);
#pragma unroll
    for (int t = 0; t < 4; t++)
#pragma unroll
        for (int i = 0; i < 4; i++) {
            int m = mt * 16 + quad * 4 + i, n = (nh * 4 + t) * 16 + bb;
            H12[(size_t)(nb0 + m) * 256 + n] = F2Bf(acc[t][i]);
        }
#pragma unroll
    for (int t = 0; t < 4; t++) acc[t] = (f32x4){0.f, 0.f, 0.f, 0.f};
    gemm_lds(A, 136, wb + 128, 256, 128, mt, nh * 4, 4, acc);
#pragma unroll
    for (int t = 0; t < 4; t++)
#pragma unroll
        for (int i = 0; i < 4; i++) {
            int m = mt * 16 + quad * 4 + i, n = (nh * 4 + t) * 16 + bb;
            H12[(size_t)(nb0 + m) * 256 + 128 + n] = F2Bf(acc[t][i]);
        }
}

// ---------------- radial -----------------------------------------------------
__global__ __launch_bounds__(256, 4) void k_radial(
    fp x, const int* __restrict__ row, const int* __restrict__ col,
    const short* __restrict__ attrT, fp cw,
    const short* __restrict__ wb, const float* __restrict__ bc,
    short* __restrict__ e1p) {
    __shared__ __attribute__((aligned(16))) short Arad[4][16 * 264];
    __shared__ float xc2[4][2][48];
    __shared__ float cwc2[4][2][16];
    __shared__ float inv16[4][16];
    const int tid = threadIdx.x, lane = tid & 63, w = tid >> 6;
    const int bb = lane & 15, quad = lane >> 4;
    const int e0 = blockIdx.x * 64 + w * 16;
    const short* Wc = wb + 32768;
    short* Ar = Arad[w];

#pragma unroll 2
    for (int m = 0; m < 16; m++) {
        const int e = e0 + m;
        const int r = row[e], c = col[e];
        const int bufi = m & 1;
        short8 arv = (short8){0, 0, 0, 0, 0, 0, 0, 0};
        short8 acv = (short8){0, 0, 0, 0, 0, 0, 0, 0};
        if (quad < 2) {
            arv = *(const short8*)(attrT + (size_t)r * 256 + bb * 16 + quad * 8);
            acv = *(const short8*)(attrT + (size_t)c * 256 + bb * 16 + quad * 8);
        }
        if (lane < 42)      xc2[w][bufi][lane] = x[(size_t)c * 42 + lane];
        else if (lane < 56) cwc2[w][bufi][lane - 42] = cw[c * 14 + (lane - 42)];
        const int iic = bb < 14 ? bb : 13;
        float xr0 = x[(size_t)r * 42 + iic * 3];
        float xr1 = x[(size_t)r * 42 + iic * 3 + 1];
        float xr2 = x[(size_t)r * 42 + iic * 3 + 2];
        float cwr = cw[r * 14 + iic];
        short8 msgv = (short8){0, 0, 0, 0, 0, 0, 0, 0};
        if (quad < 2) {
#pragma unroll
            for (int t = 0; t < 8; t++) {
                int jj = quad * 8 + t, jc = jj < 14 ? jj : 13;
                float dx = xr0 - xc2[w][bufi][jc * 3];
                float dy = xr1 - xc2[w][bufi][jc * 3 + 1];
                float dz = xr2 - xc2[w][bufi][jc * 3 + 2];
                float mm = sqrtf(dx * dx + dy * dy + dz * dz) * cwr * cwc2[w][bufi][jc];
                msgv[t] = (bb < 14 && jj < 14) ? F2Bf(mm) : (short)0;
            }
        }
        f32x4 t2 = (f32x4){0.f, 0.f, 0.f, 0.f};
        t2 = __builtin_amdgcn_mfma_f32_16x16x32_bf16(msgv, acv, t2, 0, 0, 0);
        short8 t2v;
#pragma unroll
        for (int t = 0; t < 8; t++) {
            int grp = (2 * quad + (t >> 2)) & 3;
            float v = __shfl(t2[t & 3], bb + 16 * grp, 64);
            t2v[t] = (quad < 2) ? F2Bf(v) : (short)0;
        }
        f32x4 rad = (f32x4){0.f, 0.f, 0.f, 0.f};
        rad = __builtin_amdgcn_mfma_f32_16x16x32_bf16(arv, t2v, rad, 0, 0, 0);
        float ss = rad[0] * rad[0] + rad[1] * rad[1] + rad[2] * rad[2] + rad[3] * rad[3];
#pragma unroll
        for (int off = 32; off > 0; off >>= 1) ss += __shfl_xor(ss, off, 64);
        float inv = 1.f / (sqrtf(ss) + 1.f);
        if (lane == 0) inv16[w][m] = inv;
#pragma unroll
        for (int g = 0; g < 4; g++)
            Ar[m * 264 + (quad * 4 + g) * 16 + bb] = F2Bf(rad[g] * inv);
    }
    __builtin_amdgcn_wave_barrier();

    f32x4 acc[8];
#pragma unroll
    for (int t = 0; t < 8; t++) acc[t] = (f32x4){0.f, 0.f, 0.f, 0.f};
    for (int k0 = 0; k0 < 256; k0 += 32) {
        short8 a = *(const short8*)(Ar + bb * 264 + k0 + quad * 8);
#pragma unroll
        for (int t = 0; t < 8; t++) {
            short8 b = *(const short8*)(Wc + (t * 16 + bb) * 256 + k0 + quad * 8);
            acc[t] = __builtin_amdgcn_mfma_f32_16x16x32_bf16(a, b, acc[t], 0, 0, 0);
        }
    }
    short* E1 = Ar;
#pragma unroll
    for (int t = 0; t < 8; t++)
#pragma unroll
        for (int i = 0; i < 4; i++) {
            int m = quad * 4 + i, n = t * 16 + bb;
            E1[m * 136 + n] = F2Bf(acc[t][i] + inv16[w][m] * bc[n]);
        }
    __builtin_amdgcn_wave_barrier();
    for (int p = lane; p < 256; p += 64) {
        int m = p >> 4, v = p & 15;
        *(short8*)(e1p + (size_t)(e0 + m) * 128 + v * 8) = *(const short8*)(E1 + m * 136 + v * 8);
    }
}

// ---------------- slim edge kernel: NO fp32 atomics --------------------------
__global__ __launch_bounds__(256, 6) void k_edge_split(
    fp x, const int* __restrict__ row, const int* __restrict__ col,
    const short* __restrict__ H12, short* __restrict__ e1p,  // e1p reused as ef out
    const short* __restrict__ wb,
    fp e1B, fp e2B, fp aW, fp aB, fp c1B, fp c2B,
    const float* __restrict__ csum, const float* __restrict__ poolc,
    short* __restrict__ trb) {
    __shared__ __attribute__((aligned(16))) short V1[32 * 136];
    __shared__ __attribute__((aligned(16))) short V2[32 * 136];
    __shared__ int s_r[32], s_c[32];
    __shared__ float s_ch[32][14], s_pool[32][14];
    __shared__ float s_red8[32][8], s_gate[32];

    const int tid = threadIdx.x, lane = tid & 63, w = tid >> 6;
    const int bb = lane & 15, quad = lane >> 4;
    const int mt = w & 1, nh = w >> 1;
    const int e0 = blockIdx.x * 32;

    if (tid < 32) { s_r[tid] = row[e0 + tid]; s_c[tid] = col[e0 + tid]; }
    __syncthreads();

    for (int p = tid; p < 512; p += 256) {
        int e = p >> 4, v = p & 15;
        short8 hr = *(const short8*)(H12 + (size_t)s_r[e] * 256 + v * 8);
        short8 hc = *(const short8*)(H12 + (size_t)s_c[e] * 256 + 128 + v * 8);
        short8 pp = *(const short8*)(e1p + (size_t)(e0 + e) * 128 + v * 8);
        short8 o;
#pragma unroll
        for (int j = 0; j < 8; j++)
            o[j] = F2Bf(siluf(B2F(hr[j]) + B2F(hc[j]) + B2F(pp[j]) + e1B[v * 8 + j]));
        *(short8*)(V1 + e * 136 + v * 8) = o;
    }
    __syncthreads();

    f32x4 acc[4];
#pragma unroll
    for (int t = 0; t < 4; t++) acc[t] = (f32x4){0.f, 0.f, 0.f, 0.f};
    gemm_lds(V1, 136, wb + 65536, 128, 128, mt, nh * 4, 4, acc);
#pragma unroll
    for (int t = 0; t < 4; t++)
#pragma unroll
        for (int i = 0; i < 4; i++) {
            int m = mt * 16 + quad * 4 + i, n = (nh * 4 + t) * 16 + bb;
            V2[m * 136 + n] = F2Bf(siluf(acc[t][i] + e2B[n]));
        }
    __syncthreads();

    {
        int e = tid >> 3, j = tid & 7;
        float s = 0.f;
        for (int f = j * 16; f < j * 16 + 16; f++) s += B2F(V2[e * 136 + f]) * aW[f];
        s_red8[e][j] = s;
    }
    __syncthreads();
    if (tid < 32) {
        float s = 0.f;
#pragma unroll
        for (int j = 0; j < 8; j++) s += s_red8[tid][j];
        s_gate[tid] = 1.f / (1.f + __expf(-(s + aB[0])));
    }
    __syncthreads();
    for (int p = tid; p < 32 * 128; p += 256) {
        int e = p >> 7, f = p & 127;
        V1[e * 136 + f] = F2Bf(B2F(V2[e * 136 + f]) * s_gate[e]);
    }
    __syncthreads();

    // stream gated ef back over e1p rows (this block owns them exclusively)
    for (int p = tid; p < 512; p += 256) {
        int e = p >> 4, v = p & 15;
        *(short8*)(e1p + (size_t)(e0 + e) * 128 + v * 8) = *(const short8*)(V1 + e * 136 + v * 8);
    }

#pragma unroll
    for (int t = 0; t < 4; t++) acc[t] = (f32x4){0.f, 0.f, 0.f, 0.f};
    gemm_lds(V1, 136, wb + 81920, 128, 128, mt, nh * 4, 4, acc);
    __syncthreads();
#pragma unroll
    for (int t = 0; t < 4; t++)
#pragma unroll
        for (int i = 0; i < 4; i++) {
            int m = mt * 16 + quad * 4 + i, n = (nh * 4 + t) * 16 + bb;
            V2[m * 136 + n] = F2Bf(siluf(acc[t][i] + c1B[n]));
        }
    __syncthreads();

    if (nh == 0) {
        f32x4 a4 = (f32x4){0.f, 0.f, 0.f, 0.f};
        gemm_lds(V2, 136, wb + 98304, 128, 128, mt, 0, 1, &a4);
#pragma unroll
        for (int i = 0; i < 4; i++) {
            int m = mt * 16 + quad * 4 + i;
            if (bb < 14) s_ch[m][bb] = a4[i] + c2B[bb];
        }
    }
    __syncthreads();

    if (tid < 32) {
        int t = (int)(csum[s_r[tid]] + 0.5f) - 1;
        if (t < 0) t = 0; if (t > 13) t = 13;
        int Wd = 14 - t;
        for (int i = 0; i < 14; i++) {
            int jend = i + Wd - 1; if (jend > 13) jend = 13;
            float a = 0.f;
            for (int j = i; j <= jend; j++) a += s_ch[tid][j];
            s_pool[tid][i] = a / (float)Wd;
        }
    }
    __syncthreads();

    // stream trans (bf16)
    for (int p = tid; p < 32 * 42; p += 256) {
        int e = p / 42, q = p - e * 42, i = q / 3, d = q - i * 3;
        float diff = x[(size_t)s_r[e] * 42 + q] - poolc[s_c[e] * 3 + d];
        trb[(size_t)(e0 + e) * 42 + q] = F2Bf(diff * s_pool[e][i]);
    }
}

// ---------------- node post: CSR gather aggregation --------------------------
__global__ __launch_bounds__(256, 3) void k_node_post(
    fp h, fp x, const short* __restrict__ wb,
    fp n1B, fp n2B, fp lng, fp lnb,
    const short* __restrict__ efb, const short* __restrict__ trb,
    const int* __restrict__ offc, const int* __restrict__ listc, const int* __restrict__ degc,
    const int* __restrict__ offr, const int* __restrict__ listr, const int* __restrict__ degr,
    float* __restrict__ outh, float* __restrict__ outx) {
    __shared__ __attribute__((aligned(16))) short nA[32 * 264];
    __shared__ __attribute__((aligned(16))) short nMid[32 * 136];
    __shared__ float nY[32][128];
    __shared__ float nred8[32][8];
    __shared__ float nmu[32], nrs[32];

    const int tid = threadIdx.x;
    const int wave = tid >> 6, mt = wave & 1, nh = wave >> 1;
    const int lane = tid & 63, bb = lane & 15, quad = lane >> 4;
    const int nb0 = blockIdx.x * 32;
    const short* n1Wb = wb + 100352;
    const short* n2Wb = wb + 133120;

    // h + gathered agg mean
    for (int p = tid; p < 4096; p += 256) {
        int i = p >> 7, f = p & 127, n = nb0 + i;
        nA[i * 264 + f] = F2Bf(h[(size_t)n * 128 + f]);
        int o0 = offc[n], d = degc[n];
        float s = 0.f;
        int k = 0;
        for (; k + 4 <= d; k += 4) {
            int ea = listc[o0 + k], eb2 = listc[o0 + k + 1];
            int ec = listc[o0 + k + 2], ed = listc[o0 + k + 3];
            float a0 = B2F(efb[(size_t)ea * 128 + f]);
            float a1 = B2F(efb[(size_t)eb2 * 128 + f]);
            float a2 = B2F(efb[(size_t)ec * 128 + f]);
            float a3 = B2F(efb[(size_t)ed * 128 + f]);
            s += (a0 + a1) + (a2 + a3);
        }
        for (; k < d; k++) s += B2F(efb[(size_t)listc[o0 + k] * 128 + f]);
        float dd = d > 0 ? (float)d : 1.f;
        nA[i * 264 + 128 + f] = F2Bf(s / dd);
    }
    __syncthreads();

    f32x4 acc[4];
#pragma unroll
    for (int t = 0; t < 4; t++) acc[t] = (f32x4){0.f, 0.f, 0.f, 0.f};
    gemm_lds(nA, 264, n1Wb, 256, 256, mt, nh * 4, 4, acc);
#pragma unroll
    for (int t = 0; t < 4; t++)
#pragma unroll
        for (int i = 0; i < 4; i++) {
            int m = mt * 16 + quad * 4 + i, n = (nh * 4 + t) * 16 + bb;
            nMid[m * 136 + n] = F2Bf(siluf(acc[t][i] + n1B[n]));
        }
    __syncthreads();

#pragma unroll
    for (int t = 0; t < 4; t++) acc[t] = (f32x4){0.f, 0.f, 0.f, 0.f};
    gemm_lds(nMid, 136, n2Wb, 128, 128, mt, nh * 4, 4, acc);
#pragma unroll
    for (int t = 0; t < 4; t++)
#pragma unroll
        for (int i = 0; i < 4; i++) {
            int m = mt * 16 + quad * 4 + i, n = (nh * 4 + t) * 16 + bb;
            nY[m][n] = acc[t][i] + n2B[n] + h[(size_t)(nb0 + m) * 128 + n];
        }
    __syncthreads();

    {
        int i = tid >> 3, j = tid & 7;
        float s = 0.f;
        for (int f = j * 16; f < j * 16 + 16; f++) s += nY[i][f];
        nred8[i][j] = s;
    }
    __syncthreads();
    if (tid < 32) {
        float s = 0.f;
#pragma unroll
        for (int j = 0; j < 8; j++) s += nred8[tid][j];
        nmu[tid] = s * (1.f / 128.f);
    }
    __syncthreads();
    {
        int i = tid >> 3, j = tid & 7;
        float mu = nmu[i], s = 0.f;
        for (int f = j * 16; f < j * 16 + 16; f++) { float d = nY[i][f] - mu; s += d * d; }
        nred8[i][j] = s;
    }
    __syncthreads();
    if (tid < 32) {
        float s = 0.f;
#pragma unroll
        for (int j = 0; j < 8; j++) s += nred8[tid][j];
        nrs[tid] = rsqrtf(s * (1.f / 128.f) + 1e-5f);
    }
    __syncthreads();
    for (int p = tid; p < 32 * 128; p += 256) {
        int i = p >> 7, f = p & 127;
        outh[(size_t)(nb0 + i) * 128 + f] = (nY[i][f] - nmu[i]) * nrs[i] * lng[f] + lnb[f];
    }
    // x_out via row-CSR gather
    for (int p = tid; p < 32 * 42; p += 256) {
        int i = p / 42, q = p - i * 42, n = nb0 + i;
        int o0 = offr[n], d = degr[n];
        float s = 0.f;
        int k = 0;
        for (; k + 4 <= d; k += 4) {
            int ea = listr[o0 + k], eb2 = listr[o0 + k + 1];
            int ec = listr[o0 + k + 2], ed = listr[o0 + k + 3];
            s += (B2F(trb[(size_t)ea * 42 + q]) + B2F(trb[(size_t)eb2 * 42 + q]))
               + (B2F(trb[(size_t)ec * 42 + q]) + B2F(trb[(size_t)ed * 42 + q]));
        }
        for (; k < d; k++) s += B2F(trb[(size_t)listr[o0 + k] * 42 + q]);
        float dd = d > 0 ? (float)d : 1.f;
        outx[(size_t)n * 42 + q] = x[(size_t)n * 42 + q] + s / dd;
    }
}

// ---------------- fallback: fused + atomic node post (R8 path) ---------------
__global__ __launch_bounds__(256, 3) void k_edge_fused(
    fp x, const int* __restrict__ row, const int* __restrict__ col,
    fp attr, fp cw, const short* __restrict__ hb, const short* __restrict__ wb,
    fp e1B, fp e2B, fp aW, fp aB, fp c1B, fp c2B,
    const float* __restrict__ bc, const float* __restrict__ csum,
    const float* __restrict__ poolc,
    float* __restrict__ xacc, float* __restrict__ agg,
    float* __restrict__ cntr, float* __restrict__ cntc) {
    __shared__ __attribute__((aligned(16))) short R1[13056];
    __shared__ float s_xr2[32 * 42];
    __shared__ float T[4][352];
    __shared__ int   s_r[32], s_c[32];
    __shared__ float s_inv[32];
    __shared__ float s_ch[32][14], s_pool[32][14];
    __shared__ float s_red8[32][8];
    __shared__ float s_gate[32];

    const int tid = threadIdx.x, lane = tid & 63, w = tid >> 6;
    const int bb = lane & 15, quad = lane >> 4;

    if (tid < 32) { s_r[tid] = row[blockIdx.x * 32 + tid]; s_c[tid] = col[blockIdx.x * 32 + tid]; }
    __syncthreads();

    float* slot = T[w];
    float* t2w = slot + 72;
    for (int i8 = 0; i8 < 8; i8++) {
        const int e = w * 8 + i8;
        const int r = s_r[e], cl = s_c[e];
        if (lane < 42) {
            s_xr2[e * 42 + lane] = x[(size_t)r * 42 + lane];
            slot[lane] = x[(size_t)cl * 42 + lane];
        }
        if (lane < 14)      slot[42 + lane] = cw[r * 14 + lane];
        else if (lane < 28) slot[56 + (lane - 14)] = cw[cl * 14 + (lane - 14)];
        __builtin_amdgcn_wave_barrier();

        const int iic = bb < 14 ? bb : 13;
        float xr0 = s_xr2[e * 42 + iic * 3], xr1 = s_xr2[e * 42 + iic * 3 + 1],
              xr2v = s_xr2[e * 42 + iic * 3 + 2];
        float cwri = slot[42 + iic];
        short8 msgv, acv;
#pragma unroll
        for (int t = 0; t < 8; t++) {
            int jj = quad * 8 + t, jc = jj < 14 ? jj : 13;
            float dx = xr0 - slot[jc * 3], dy = xr1 - slot[jc * 3 + 1], dz = xr2v - slot[jc * 3 + 2];
            float m = sqrtf(dx * dx + dy * dy + dz * dz) * cwri * slot[56 + jc];
            msgv[t] = (bb < 14 && jj < 14) ? F2B(m) : (short)0;
            acv[t] = F2B(attr[(size_t)cl * 224 + jc * 16 + bb]);
        }
        f32x4 t2 = (f32x4){0.f, 0.f, 0.f, 0.f};
        t2 = __builtin_amdgcn_mfma_f32_16x16x32_bf16(msgv, acv, t2, 0, 0, 0);
#pragma unroll
        for (int g = 0; g < 4; g++) t2w[(quad * 4 + g) * 17 + bb] = t2[g];
        __builtin_amdgcn_wave_barrier();

        short8 arv, t2v;
#pragma unroll
        for (int t = 0; t < 8; t++) {
            int kk = quad * 8 + t, kc = kk < 16 ? kk : 15;
            t2v[t] = F2B(t2w[kc * 17 + bb]);
            arv[t] = (kk < 14) ? F2B(attr[(size_t)r * 224 + kk * 16 + bb]) : (short)0;
        }
        f32x4 rad = (f32x4){0.f, 0.f, 0.f, 0.f};
        rad = __builtin_amdgcn_mfma_f32_16x16x32_bf16(arv, t2v, rad, 0, 0, 0);

        float ss = rad[0] * rad[0] + rad[1] * rad[1] + rad[2] * rad[2] + rad[3] * rad[3];
#pragma unroll
        for (int off = 32; off > 0; off >>= 1) ss += __shfl_xor(ss, off, 64);
        float inv = 1.f / (sqrtf(ss) + 1.f);
        if (lane == 0) s_inv[e] = inv;
#pragma unroll
        for (int g = 0; g < 4; g++)
            R1[e * 264 + (quad * 4 + g) * 16 + bb] = F2B(rad[g] * inv);
        __builtin_amdgcn_wave_barrier();
    }
    __syncthreads();

    const int mt = w & 1, nh = w >> 1;
    const int m_ = mt * 16 + bb;
    f32x4 acc[4];
#pragma unroll
    for (int t = 0; t < 4; t++) acc[t] = (f32x4){0.f, 0.f, 0.f, 0.f};
    {
        const short* ar_ = hb + (size_t)s_r[m_] * 128 + quad * 8;
        const short* ac_ = hb + (size_t)s_c[m_] * 128 + quad * 8;
        gemm_grow(ar_, wb, 256, 128, nh * 4, 4, acc);
        gemm_grow(ac_, wb + 128, 256, 128, nh * 4, 4, acc);
        gemm_lds(R1, 264, wb + 32768, 256, 256, mt, nh * 4, 4, acc);
    }
    __syncthreads();
    short* V1 = R1;
    short* V2 = R1 + 4352;
    short* C1O = R1 + 8704;
#pragma unroll
    for (int t = 0; t < 4; t++)
#pragma unroll
        for (int i = 0; i < 4; i++) {
            int m = mt * 16 + quad * 4 + i, n = (nh * 4 + t) * 16 + bb;
            V1[m * 136 + n] = F2B(siluf(acc[t][i] + e1B[n] + bc[n] * s_inv[m]));
        }
    __syncthreads();

#pragma unroll
    for (int t = 0; t < 4; t++) acc[t] = (f32x4){0.f, 0.f, 0.f, 0.f};
    gemm_lds(V1, 136, wb + 65536, 128, 128, mt, nh * 4, 4, acc);
    __syncthreads();
#pragma unroll
    for (int t = 0; t < 4; t++)
#pragma unroll
        for (int i = 0; i < 4; i++) {
            int m = mt * 16 + quad * 4 + i, n = (nh * 4 + t) * 16 + bb;
            V2[m * 136 + n] = F2B(siluf(acc[t][i] + e2B[n]));
        }
    __syncthreads();

    {
        int e = tid >> 3, j = tid & 7;
        float s = 0.f;
        for (int f = j * 16; f < j * 16 + 16; f++) s += B2F(V2[e * 136 + f]) * aW[f];
        s_red8[e][j] = s;
    }
    __syncthreads();
    if (tid < 32) {
        float s = 0.f;
#pragma unroll
        for (int j = 0; j < 8; j++) s += s_red8[tid][j];
        s_gate[tid] = 1.f / (1.f + __expf(-(s + aB[0])));
    }
    __syncthreads();
    for (int p = tid; p < 32 * 128; p += 256) {
        int e = p >> 7, f = p & 127;
        V1[e * 136 + f] = F2B(B2F(V2[e * 136 + f]) * s_gate[e]);
    }
    __syncthreads();

#pragma unroll
    for (int t = 0; t < 4; t++) acc[t] = (f32x4){0.f, 0.f, 0.f, 0.f};
    gemm_lds(V1, 136, wb + 81920, 128, 128, mt, nh * 4, 4, acc);
    __syncthreads();
#pragma unroll
    for (int t = 0; t < 4; t++)
#pragma unroll
        for (int i = 0; i < 4; i++) {
            int m = mt * 16 + quad * 4 + i, n = (nh * 4 + t) * 16 + bb;
            C1O[m * 136 + n] = F2B(siluf(acc[t][i] + c1B[n]));
        }
    __syncthreads();

    if (nh == 0) {
        f32x4 a4 = (f32x4){0.f, 0.f, 0.f, 0.f};
        gemm_lds(C1O, 136, wb + 98304, 128, 128, mt, 0, 1, &a4);
#pragma unroll
        for (int i = 0; i < 4; i++) {
            int m = mt * 16 + quad * 4 + i;
            if (bb < 14) s_ch[m][bb] = a4[i] + c2B[bb];
        }
    }
    __syncthreads();

    if (tid < 32) {
        int t = (int)(csum[s_r[tid]] + 0.5f) - 1;
        if (t < 0) t = 0; if (t > 13) t = 13;
        int Wd = 14 - t;
        for (int i = 0; i < 14; i++) {
            int jend = i + Wd - 1; if (jend > 13) jend = 13;
            float a = 0.f;
            for (int j = i; j <= jend; j++) a += s_ch[tid][j];
            s_pool[tid][i] = a / (float)Wd;
        }
    }
    __syncthreads();

    for (int p = tid; p < 32 * 42; p += 256) {
        int e = p / 42, q = p - e * 42, i = q / 3, d = q - i * 3;
        float diff = s_xr2[e * 42 + q] - poolc[s_c[e] * 3 + d];
        atomicAdd(&xacc[(size_t)s_r[e] * 42 + q], diff * s_pool[e][i]);
    }
    for (int p = tid; p < 32 * 128; p += 256) {
        int e = p >> 7, f = p & 127;
        atomicAdd(&agg[(size_t)s_c[e] * 128 + f], B2F(V1[e * 136 + f]));
    }
    if (tid < 32) {
        atomicAdd(&cntr[s_r[tid]], 1.f);
        atomicAdd(&cntc[s_c[tid]], 1.f);
    }
}

__global__ __launch_bounds__(256, 2) void k_node_post_fb(
    fp h, fp x, const short* __restrict__ wb,
    fp n1B, fp n2B, fp lng, fp lnb,
    const float* __restrict__ agg, const float* __restrict__ cntc,
    const float* __restrict__ xacc, const float* __restrict__ cntr,
    float* __restrict__ outh, float* __restrict__ outx) {
    __shared__ __attribute__((aligned(16))) short nA[32 * 264];
    __shared__ __attribute__((aligned(16))) short nMid[32 * 136];
    __shared__ float nY[32][128];
    __shared__ float nred8[32][8];
    __shared__ float nmu[32], nrs[32];

    const int tid = threadIdx.x;
    const int wave = tid >> 6, mt = wave & 1, nh = wave >> 1;
    const int lane = tid & 63, bb = lane & 15, quad = lane >> 4;
    const int nb0 = blockIdx.x * 32;
    const short* n1Wb = wb + 100352;
    const short* n2Wb = wb + 133120;

    for (int p = tid; p < 32 * 128; p += 256) {
        int i = p >> 7, f = p & 127;
        int n = nb0 + i;
        nA[i * 264 + f] = F2Bf(h[(size_t)n * 128 + f]);
        float cc = cntc[n]; if (cc < 1.f) cc = 1.f;
        nA[i * 264 + 128 + f] = F2Bf(agg[(size_t)n * 128 + f] / cc);
    }
    __syncthreads();

    f32x4 acc[4];
#pragma unroll
    for (int t = 0; t < 4; t++) acc[t] = (f32x4){0.f, 0.f, 0.f, 0.f};
    gemm_lds(nA, 264, n1Wb, 256, 256, mt, nh * 4, 4, acc);
#pragma unroll
    for (int t = 0; t < 4; t++)
#pragma unroll
        for (int i = 0; i < 4; i++) {
            int m = mt * 16 + quad * 4 + i, n = (nh * 4 + t) * 16 + bb;
            nMid[m * 136 + n] = F2Bf(siluf(acc[t][i] + n1B[n]));
        }
    __syncthreads();

#pragma unroll
    for (int t = 0; t < 4; t++) acc[t] = (f32x4){0.f, 0.f, 0.f, 0.f};
    gemm_lds(nMid, 136, n2Wb, 128, 128, mt, nh * 4, 4, acc);
#pragma unroll
    for (int t = 0; t < 4; t++)
#pragma unroll
        for (int i = 0; i < 4; i++) {
            int m = mt * 16 + quad * 4 + i, n = (nh * 4 + t) * 16 + bb;
            nY[m][n] = acc[t][i] + n2B[n] + h[(size_t)(nb0 + m) * 128 + n];
        }
    __syncthreads();

    {
        int i = tid >> 3, j = tid & 7;
        float s = 0.f;
        for (int f = j * 16; f < j * 16 + 16; f++) s += nY[i][f];
        nred8[i][j] = s;
    }
    __syncthreads();
    if (tid < 32) {
        float s = 0.f;
#pragma unroll
        for (int j = 0; j < 8; j++) s += nred8[tid][j];
        nmu[tid] = s * (1.f / 128.f);
    }
    __syncthreads();
    {
        int i = tid >> 3, j = tid & 7;
        float mu = nmu[i], s = 0.f;
        for (int f = j * 16; f < j * 16 + 16; f++) { float d = nY[i][f] - mu; s += d * d; }
        nred8[i][j] = s;
    }
    __syncthreads();
    if (tid < 32) {
        float s = 0.f;
#pragma unroll
        for (int j = 0; j < 8; j++) s += nred8[tid][j];
        nrs[tid] = rsqrtf(s * (1.f / 128.f) + 1e-5f);
    }
    __syncthreads();
    for (int p = tid; p < 32 * 128; p += 256) {
        int i = p >> 7, f = p & 127;
        outh[(size_t)(nb0 + i) * 128 + f] = (nY[i][f] - nmu[i]) * nrs[i] * lng[f] + lnb[f];
    }
    for (int p = tid; p < 32 * 42; p += 256) {
        int i = p / 42, q = p - i * 42;
        int n = nb0 + i;
        float cr = cntr[n]; if (cr < 1.f) cr = 1.f;
        outx[(size_t)n * 42 + q] = x[(size_t)n * 42 + q] + xacc[(size_t)n * 42 + q] / cr;
    }
}

extern "C" void kernel_launch(void* const* d_in, const int* in_sizes, int n_in,
                              void* d_out, int out_size, void* d_ws, size_t ws_size,
                              hipStream_t stream) {
    fp h   = (fp)d_in[0];
    fp x   = (fp)d_in[1];
    const int* row = (const int*)d_in[2];
    const int* col = (const int*)d_in[3];
    fp attr= (fp)d_in[4];
    fp cw  = (fp)d_in[5];
    fp rW  = (fp)d_in[6];  fp rB  = (fp)d_in[7];
    fp e1W = (fp)d_in[8];  fp e1B = (fp)d_in[9];
    fp e2W = (fp)d_in[10]; fp e2B = (fp)d_in[11];
    fp aW  = (fp)d_in[12]; fp aB  = (fp)d_in[13];
    fp c1W = (fp)d_in[14]; fp c1B = (fp)d_in[15];
    fp c2W = (fp)d_in[16]; fp c2B = (fp)d_in[17];
    fp n1W = (fp)d_in[18]; fp n1B = (fp)d_in[19];
    fp n2W = (fp)d_in[20]; fp n2B = (fp)d_in[21];
    fp lng = (fp)d_in[22]; fp lnb = (fp)d_in[23];

    // f32-unit offsets:
    // degc 0 | degr 20000 | curc 40000 | curr 60000 | offc 80000 | offr 100008
    // listc 120016 | listr 440016 | csum 760016 | pool 780016 | bc 840016
    // hb 840144 | wb 2120144 | H12 2194896 | e1p/ef 4754896 | trb 25234896
    // end 31954896  (127.8 MB)
    float* ws    = (float*)d_ws;
    int*   degc  = (int*)ws;
    int*   degr  = (int*)(ws + 20000);
    int*   curc  = (int*)(ws + 40000);
    int*   curr  = (int*)(ws + 60000);
    int*   offc  = (int*)(ws + 80000);
    int*   offr  = (int*)(ws + 100008);
    int*   listc = (int*)(ws + 120016);
    int*   listr = (int*)(ws + 440016);
    float* csum  = ws + 760016;
    float* pool  = ws + 780016;
    float* bc    = ws + 840016;
    short* hb    = (short*)(ws + 840144);
    short* wb    = (short*)(ws + 2120144);
    short* H12   = (short*)(ws + 2194896);
    short* e1p   = (short*)(ws + 4754896);
    short* trb   = (short*)(ws + 25234896);
    short* attrT = H12 + 0;  // placeholder; real attrT below

    const size_t need = 31954896ull * 4ull + (size_t)NN * 256 * 2; // + attrT tail
    // attrT appended at the end:
    short* attrT_real = (short*)(ws + 31954896);
    attrT = attrT_real;

    if (ws_size >= need) {
        hipMemsetAsync(d_ws, 0, 40000 * sizeof(int), stream);  // degc+degr
        k_prep_w<<<(149504 + 255) / 256, 256, 0, stream>>>(e1W, e2W, c1W, c2W, n1W, n2W, wb);
        k_fold<<<128, 256, 0, stream>>>(e1W, rW, rB, wb, bc);
        k_prep_h<<<(NN * 128 + 255) / 256, 256, 0, stream>>>(h, hb);
        k_node_pre<<<(NN + 255) / 256, 256, 0, stream>>>(x, cw, csum, pool);
        k_prep_attrT<<<(NN * 256 + 255) / 256, 256, 0, stream>>>(attr, attrT);
        k_deg<<<(NE + 255) / 256, 256, 0, stream>>>(row, col, degr, degc);
        k_scan<<<1, 256, 0, stream>>>(degc, degr, offc, offr, curc, curr);
        k_fill<<<(NE + 255) / 256, 256, 0, stream>>>(row, col, curr, curc, listr, listc);
        k_hw<<<NN / 32, 256, 0, stream>>>(hb, wb, H12);
        k_radial<<<NE / 64, 256, 0, stream>>>(x, row, col, attrT, cw, wb, bc, e1p);
        k_edge_split<<<NE / 32, 256, 0, stream>>>(x, row, col, H12, e1p, wb,
                                                  e1B, e2B, aW, aB, c1B, c2B,
                                                  csum, pool, trb);
        float* outh = (float*)d_out;
        float* outx = outh + NN * 128;
        k_node_post<<<NN / 32, 256, 0, stream>>>(h, x, wb, n1B, n2B, lng, lnb,
                                                 e1p, trb,
                                                 offc, listc, degc,
                                                 offr, listr, degr,
                                                 outh, outx);
    } else {
        // fallback: R8 fused path with atomics (buffers in low region)
        float* xacc = ws + 4754896;
        float* agg  = ws + 5594896;
        float* cntr = ws + 8154896;
        float* cntc = ws + 8174896;
        hipMemsetAsync(ws + 4754896, 0, 3440000 * sizeof(float), stream);
        k_prep_w<<<(149504 + 255) / 256, 256, 0, stream>>>(e1W, e2W, c1W, c2W, n1W, n2W, wb);
        k_fold<<<128, 256, 0, stream>>>(e1W, rW, rB, wb, bc);
        k_prep_h<<<(NN * 128 + 255) / 256, 256, 0, stream>>>(h, hb);
        k_node_pre<<<(NN + 255) / 256, 256, 0, stream>>>(x, cw, csum, pool);
        k_edge_fused<<<NE / 32, 256, 0, stream>>>(x, row, col, attr, cw, hb, wb,
                                                  e1B, e2B, aW, aB, c1B, c2B,
                                                  bc, csum, pool, xacc, agg, cntr, cntc);
        float* outh = (float*)d_out;
        float* outx = outh + NN * 128;
        k_node_post_fb<<<NN / 32, 256, 0, stream>>>(h, x, wb, n1B, n2B, lng, lnb,
                                                    agg, cntc, xacc, cntr, outh, outx);
    }
}

// Round 10
// 962.346 us; speedup vs baseline: 1.0410x; 1.0410x over previous
//
#include <hip/hip_runtime.h>
#include <math.h>

#define NN 20000
#define NE 320000

typedef const float* fp;
typedef short short8 __attribute__((ext_vector_type(8)));
typedef float f32x4 __attribute__((ext_vector_type(4)));

__device__ __forceinline__ short F2B(float f) {
    unsigned u = __float_as_uint(f);
    return (short)((u + 0x7fffu + ((u >> 16) & 1u)) >> 16);
}
__device__ __forceinline__ short F2Bf(float f) {
    return (short)((__float_as_uint(f) + 0x8000u) >> 16);
}
__device__ __forceinline__ float B2F(short s) {
    return __uint_as_float(((unsigned)(unsigned short)s) << 16);
}
__device__ __forceinline__ float siluf(float v) { return v / (1.f + __expf(-v)); }

// wb layout (shorts): 0 e1hh[128][256] | 32768 Wc | 65536 e2W | 81920 c1W
// 98304 c2W[16][128] | 100352 n1W | 133120 n2W | end 149504
__global__ void k_prep_w(fp e1W, fp e2W, fp c1W, fp c2W, fp n1W, fp n2W,
                         short* __restrict__ wb) {
    int i = blockIdx.x * 256 + threadIdx.x;
    if (i >= 149504) return;
    if (i >= 32768 && i < 65536) return;
    float v;
    if (i < 32768)       { int o = i >> 8, k = i & 255; v = e1W[o * 384 + k]; }
    else if (i < 81920)  v = e2W[i - 65536];
    else if (i < 98304)  v = c1W[i - 81920];
    else if (i < 100352) { int q = i - 98304; v = (q < 1792) ? c2W[q] : 0.f; }
    else if (i < 133120) v = n1W[i - 100352];
    else                 v = n2W[i - 133120];
    wb[i] = F2B(v);
}

__global__ void k_fold(fp e1W, fp rW, fp rB, short* __restrict__ wb,
                       float* __restrict__ bc) {
    int o = blockIdx.x, k = threadIdx.x;
    float acc = 0.f;
    for (int m = 0; m < 128; m++) acc += e1W[o * 384 + 256 + m] * rW[m * 256 + k];
    wb[32768 + o * 256 + k] = F2B(acc);
    if (k == 0) {
        float b = 0.f;
        for (int m = 0; m < 128; m++) b += e1W[o * 384 + 256 + m] * rB[m];
        bc[o] = b;
    }
}

__global__ void k_prep_h(fp h, short* __restrict__ hb) {
    int i = blockIdx.x * 256 + threadIdx.x;
    if (i < NN * 128) hb[i] = F2B(h[i]);
}

__global__ void k_prep_attrT(fp attr, short* __restrict__ aT) {
    int i = blockIdx.x * 256 + threadIdx.x;
    if (i >= NN * 256) return;
    int n = i >> 8, rem = i & 255, c = rem >> 4, a = rem & 15;
    float v = (c < 14) ? attr[(size_t)n * 224 + c * 16 + a] : 0.f;
    aT[(size_t)n * 256 + a * 16 + c] = F2B(v);
}

__global__ void k_node_pre(fp x, fp cw, float* __restrict__ csum, float* __restrict__ pool) {
    int n = blockIdx.x * blockDim.x + threadIdx.x;
    if (n >= NN) return;
    float cnt = 0.f, px = 0.f, py = 0.f, pz = 0.f;
#pragma unroll
    for (int c = 0; c < 14; c++) {
        float w = cw[n * 14 + c];
        if (w != 0.f) {
            cnt += 1.f;
            px += x[(n * 14 + c) * 3 + 0];
            py += x[(n * 14 + c) * 3 + 1];
            pz += x[(n * 14 + c) * 3 + 2];
        }
    }
    if (cnt < 1.f) cnt = 1.f;
    csum[n] = cnt;
    pool[n * 3 + 0] = px / cnt;
    pool[n * 3 + 1] = py / cnt;
    pool[n * 3 + 2] = pz / cnt;
}

// ---------------- CSR build --------------------------------------------------
__global__ void k_deg(const int* __restrict__ row, const int* __restrict__ col,
                      int* __restrict__ degr, int* __restrict__ degc) {
    int e = blockIdx.x * 256 + threadIdx.x;
    if (e >= NE) return;
    atomicAdd(&degr[row[e]], 1);
    atomicAdd(&degc[col[e]], 1);
}

__global__ void k_scan(const int* __restrict__ degc, const int* __restrict__ degr,
                       int* __restrict__ offc, int* __restrict__ offr,
                       int* __restrict__ curc, int* __restrict__ curr) {
    __shared__ int part[256];
    const int t = threadIdx.x;
    const int CH = (NN + 255) / 256;
    for (int a = 0; a < 2; a++) {
        const int* deg = a ? degr : degc;
        int* off = a ? offr : offc;
        int* cur = a ? curr : curc;
        int base = t * CH;
        int s = 0;
        for (int k = 0; k < CH; k++) { int idx = base + k; if (idx < NN) s += deg[idx]; }
        part[t] = s;
        __syncthreads();
        for (int d = 1; d < 256; d <<= 1) {
            int v = (t >= d) ? part[t - d] : 0;
            __syncthreads();
            part[t] += v;
            __syncthreads();
        }
        int run = (t == 0) ? 0 : part[t - 1];
        for (int k = 0; k < CH; k++) {
            int idx = base + k;
            if (idx < NN) { off[idx] = run; cur[idx] = run; run += deg[idx]; }
        }
        if (t == 255) off[NN] = run;
        __syncthreads();
    }
}

// pos-indexed edge tables: rowp/colp (col-sorted positions), trpos = row-rank
__global__ void k_fill(const int* __restrict__ row, const int* __restrict__ col,
                       int* __restrict__ curr, int* __restrict__ curc,
                       int* __restrict__ rowp, int* __restrict__ colp,
                       int* __restrict__ trpos) {
    int e = blockIdx.x * 256 + threadIdx.x;
    if (e >= NE) return;
    int r = row[e], c = col[e];
    int pr = atomicAdd(&curr[r], 1);
    int pc = atomicAdd(&curc[c], 1);
    rowp[pc] = r;
    colp[pc] = c;
    trpos[pc] = pr;
}

__device__ __forceinline__ void gemm_lds(const short* __restrict__ A, int sA,
                                         const short* __restrict__ W, int Ws, int K,
                                         int mt, int nt0, int nts, f32x4* acc) {
    const int lane = threadIdx.x & 63;
    const short* ap = A + (mt * 16 + (lane & 15)) * sA + ((lane >> 4) * 8);
    for (int k0 = 0; k0 < K; k0 += 32) {
        short8 a = *(const short8*)(ap + k0);
#pragma unroll
        for (int t = 0; t < nts; t++) {
            short8 b = *(const short8*)(W + ((nt0 + t) * 16 + (lane & 15)) * Ws + k0 + ((lane >> 4) * 8));
            acc[t] = __builtin_amdgcn_mfma_f32_16x16x32_bf16(a, b, acc[t], 0, 0, 0);
        }
    }
}
__device__ __forceinline__ void gemm_grow(const short* __restrict__ arow,
                                          const short* __restrict__ W, int Ws, int K,
                                          int nt0, int nts, f32x4* acc) {
    const int lane = threadIdx.x & 63;
    for (int k0 = 0; k0 < K; k0 += 32) {
        short8 a = *(const short8*)(arow + k0);
#pragma unroll
        for (int t = 0; t < nts; t++) {
            short8 b = *(const short8*)(W + ((nt0 + t) * 16 + (lane & 15)) * Ws + k0 + ((lane >> 4) * 8));
            acc[t] = __builtin_amdgcn_mfma_f32_16x16x32_bf16(a, b, acc[t], 0, 0, 0);
        }
    }
}

// ---------------- H12 --------------------------------------------------------
__global__ __launch_bounds__(256, 2) void k_hw(const short* __restrict__ hb,
                                               const short* __restrict__ wb,
                                               short* __restrict__ H12) {
    __shared__ __attribute__((aligned(16))) short A[32 * 136];
    const int tid = threadIdx.x, lane = tid & 63, w = tid >> 6;
    const int bb = lane & 15, quad = lane >> 4;
    const int mt = w & 1, nh = w >> 1, nb0 = blockIdx.x * 32;
    for (int p = tid; p < 512; p += 256) {
        int i = p >> 4, v = p & 15;
        *(short8*)(A + i * 136 + v * 8) = *(const short8*)(hb + (size_t)(nb0 + i) * 128 + v * 8);
    }
    __syncthreads();
    f32x4 acc[4];
#pragma unroll
    for (int t = 0; t < 4; t++) acc[t] = (f32x4){0.f, 0.f, 0.f, 0.f};
    gemm_lds(A, 136, wb, 256, 128, mt, nh * 4, 4, acc);
#pragma unroll
    for (int t = 0; t < 4; t++)
#pragma unroll
        for (int i = 0; i < 4; i++) {
            int m = mt * 16 + quad * 4 + i, n = (nh * 4 + t) * 16 + bb;
            H12[(size_t)(nb0 + m) * 256 + n] = F2Bf(acc[t][i]);
        }
#pragma unroll
    for (int t = 0; t < 4; t++) acc[t] = (f32x4){0.f, 0.f, 0.f, 0.f};
    gemm_lds(A, 136, wb + 128, 256, 128, mt, nh * 4, 4, acc);
#pragma unroll
    for (int t = 0; t < 4; t++)
#pragma unroll
        for (int i = 0; i < 4; i++) {
            int m = mt * 16 + quad * 4 + i, n = (nh * 4 + t) * 16 + bb;
            H12[(size_t)(nb0 + m) * 256 + 128 + n] = F2Bf(acc[t][i]);
        }
}

// ---------------- radial (pos-order; c clustered) ----------------------------
__global__ __launch_bounds__(256, 4) void k_radial(
    fp x, const int* __restrict__ rowp, const int* __restrict__ colp,
    const short* __restrict__ attrT, fp cw,
    const short* __restrict__ wb, const float* __restrict__ bc,
    short* __restrict__ e1p) {
    __shared__ __attribute__((aligned(16))) short Arad[4][16 * 264];
    __shared__ float xc2[4][2][48];
    __shared__ float cwc2[4][2][16];
    __shared__ float inv16[4][16];
    const int tid = threadIdx.x, lane = tid & 63, w = tid >> 6;
    const int bb = lane & 15, quad = lane >> 4;
    const int e0 = blockIdx.x * 64 + w * 16;
    const short* Wc = wb + 32768;
    short* Ar = Arad[w];

#pragma unroll 2
    for (int m = 0; m < 16; m++) {
        const int e = e0 + m;
        const int r = rowp[e], c = colp[e];
        const int bufi = m & 1;
        short8 arv = (short8){0, 0, 0, 0, 0, 0, 0, 0};
        short8 acv = (short8){0, 0, 0, 0, 0, 0, 0, 0};
        if (quad < 2) {
            arv = *(const short8*)(attrT + (size_t)r * 256 + bb * 16 + quad * 8);
            acv = *(const short8*)(attrT + (size_t)c * 256 + bb * 16 + quad * 8);
        }
        if (lane < 42)      xc2[w][bufi][lane] = x[(size_t)c * 42 + lane];
        else if (lane < 56) cwc2[w][bufi][lane - 42] = cw[c * 14 + (lane - 42)];
        const int iic = bb < 14 ? bb : 13;
        float xr0 = x[(size_t)r * 42 + iic * 3];
        float xr1 = x[(size_t)r * 42 + iic * 3 + 1];
        float xr2 = x[(size_t)r * 42 + iic * 3 + 2];
        float cwr = cw[r * 14 + iic];
        short8 msgv = (short8){0, 0, 0, 0, 0, 0, 0, 0};
        if (quad < 2) {
#pragma unroll
            for (int t = 0; t < 8; t++) {
                int jj = quad * 8 + t, jc = jj < 14 ? jj : 13;
                float dx = xr0 - xc2[w][bufi][jc * 3];
                float dy = xr1 - xc2[w][bufi][jc * 3 + 1];
                float dz = xr2 - xc2[w][bufi][jc * 3 + 2];
                float mm = sqrtf(dx * dx + dy * dy + dz * dz) * cwr * cwc2[w][bufi][jc];
                msgv[t] = (bb < 14 && jj < 14) ? F2Bf(mm) : (short)0;
            }
        }
        f32x4 t2 = (f32x4){0.f, 0.f, 0.f, 0.f};
        t2 = __builtin_amdgcn_mfma_f32_16x16x32_bf16(msgv, acv, t2, 0, 0, 0);
        short8 t2v;
#pragma unroll
        for (int t = 0; t < 8; t++) {
            int grp = (2 * quad + (t >> 2)) & 3;
            float v = __shfl(t2[t & 3], bb + 16 * grp, 64);
            t2v[t] = (quad < 2) ? F2Bf(v) : (short)0;
        }
        f32x4 rad = (f32x4){0.f, 0.f, 0.f, 0.f};
        rad = __builtin_amdgcn_mfma_f32_16x16x32_bf16(arv, t2v, rad, 0, 0, 0);
        float ss = rad[0] * rad[0] + rad[1] * rad[1] + rad[2] * rad[2] + rad[3] * rad[3];
#pragma unroll
        for (int off = 32; off > 0; off >>= 1) ss += __shfl_xor(ss, off, 64);
        float inv = 1.f / (sqrtf(ss) + 1.f);
        if (lane == 0) inv16[w][m] = inv;
#pragma unroll
        for (int g = 0; g < 4; g++)
            Ar[m * 264 + (quad * 4 + g) * 16 + bb] = F2Bf(rad[g] * inv);
    }
    __builtin_amdgcn_wave_barrier();

    f32x4 acc[8];
#pragma unroll
    for (int t = 0; t < 8; t++) acc[t] = (f32x4){0.f, 0.f, 0.f, 0.f};
    for (int k0 = 0; k0 < 256; k0 += 32) {
        short8 a = *(const short8*)(Ar + bb * 264 + k0 + quad * 8);
#pragma unroll
        for (int t = 0; t < 8; t++) {
            short8 b = *(const short8*)(Wc + (t * 16 + bb) * 256 + k0 + quad * 8);
            acc[t] = __builtin_amdgcn_mfma_f32_16x16x32_bf16(a, b, acc[t], 0, 0, 0);
        }
    }
    short* E1 = Ar;
#pragma unroll
    for (int t = 0; t < 8; t++)
#pragma unroll
        for (int i = 0; i < 4; i++) {
            int m = quad * 4 + i, n = t * 16 + bb;
            E1[m * 136 + n] = F2Bf(acc[t][i] + inv16[w][m] * bc[n]);
        }
    __builtin_amdgcn_wave_barrier();
    for (int p = lane; p < 256; p += 64) {
        int m = p >> 4, v = p & 15;
        *(short8*)(e1p + (size_t)(e0 + m) * 128 + v * 8) = *(const short8*)(E1 + m * 136 + v * 8);
    }
}

// ---------------- edge kernel (pos-order, streaming outputs) -----------------
__global__ __launch_bounds__(256, 6) void k_edge_split(
    fp x, const int* __restrict__ rowp, const int* __restrict__ colp,
    const int* __restrict__ trpos,
    const short* __restrict__ H12, short* __restrict__ e1p,
    const short* __restrict__ wb,
    fp e1B, fp e2B, fp aW, fp aB, fp c1B, fp c2B,
    const float* __restrict__ csum, const float* __restrict__ poolc,
    short* __restrict__ trb) {
    __shared__ __attribute__((aligned(16))) short V1[32 * 136];
    __shared__ __attribute__((aligned(16))) short V2[32 * 136];
    __shared__ int s_r[32], s_c[32], s_tp[32];
    __shared__ float s_ch[32][14], s_pool[32][14];
    __shared__ float s_red8[32][8], s_gate[32];

    const int tid = threadIdx.x, lane = tid & 63, w = tid >> 6;
    const int bb = lane & 15, quad = lane >> 4;
    const int mt = w & 1, nh = w >> 1;
    const int e0 = blockIdx.x * 32;

    if (tid < 32) {
        s_r[tid] = rowp[e0 + tid];
        s_c[tid] = colp[e0 + tid];
        s_tp[tid] = trpos[e0 + tid];
    }
    __syncthreads();

    for (int p = tid; p < 512; p += 256) {
        int e = p >> 4, v = p & 15;
        short8 hr = *(const short8*)(H12 + (size_t)s_r[e] * 256 + v * 8);
        short8 hc = *(const short8*)(H12 + (size_t)s_c[e] * 256 + 128 + v * 8);
        short8 pp = *(const short8*)(e1p + (size_t)(e0 + e) * 128 + v * 8);
        short8 o;
#pragma unroll
        for (int j = 0; j < 8; j++)
            o[j] = F2Bf(siluf(B2F(hr[j]) + B2F(hc[j]) + B2F(pp[j]) + e1B[v * 8 + j]));
        *(short8*)(V1 + e * 136 + v * 8) = o;
    }
    __syncthreads();

    f32x4 acc[4];
#pragma unroll
    for (int t = 0; t < 4; t++) acc[t] = (f32x4){0.f, 0.f, 0.f, 0.f};
    gemm_lds(V1, 136, wb + 65536, 128, 128, mt, nh * 4, 4, acc);
#pragma unroll
    for (int t = 0; t < 4; t++)
#pragma unroll
        for (int i = 0; i < 4; i++) {
            int m = mt * 16 + quad * 4 + i, n = (nh * 4 + t) * 16 + bb;
            V2[m * 136 + n] = F2Bf(siluf(acc[t][i] + e2B[n]));
        }
    __syncthreads();

    {
        int e = tid >> 3, j = tid & 7;
        float s = 0.f;
        for (int f = j * 16; f < j * 16 + 16; f++) s += B2F(V2[e * 136 + f]) * aW[f];
        s_red8[e][j] = s;
    }
    __syncthreads();
    if (tid < 32) {
        float s = 0.f;
#pragma unroll
        for (int j = 0; j < 8; j++) s += s_red8[tid][j];
        s_gate[tid] = 1.f / (1.f + __expf(-(s + aB[0])));
    }
    __syncthreads();
    for (int p = tid; p < 32 * 128; p += 256) {
        int e = p >> 7, f = p & 127;
        V1[e * 136 + f] = F2Bf(B2F(V2[e * 136 + f]) * s_gate[e]);
    }
    __syncthreads();

    // gated ef streamed back (col-sorted rows; block-exclusive)
    for (int p = tid; p < 512; p += 256) {
        int e = p >> 4, v = p & 15;
        *(short8*)(e1p + (size_t)(e0 + e) * 128 + v * 8) = *(const short8*)(V1 + e * 136 + v * 8);
    }

#pragma unroll
    for (int t = 0; t < 4; t++) acc[t] = (f32x4){0.f, 0.f, 0.f, 0.f};
    gemm_lds(V1, 136, wb + 81920, 128, 128, mt, nh * 4, 4, acc);
    __syncthreads();
#pragma unroll
    for (int t = 0; t < 4; t++)
#pragma unroll
        for (int i = 0; i < 4; i++) {
            int m = mt * 16 + quad * 4 + i, n = (nh * 4 + t) * 16 + bb;
            V2[m * 136 + n] = F2Bf(siluf(acc[t][i] + c1B[n]));
        }
    __syncthreads();

    if (nh == 0) {
        f32x4 a4 = (f32x4){0.f, 0.f, 0.f, 0.f};
        gemm_lds(V2, 136, wb + 98304, 128, 128, mt, 0, 1, &a4);
#pragma unroll
        for (int i = 0; i < 4; i++) {
            int m = mt * 16 + quad * 4 + i;
            if (bb < 14) s_ch[m][bb] = a4[i] + c2B[bb];
        }
    }
    __syncthreads();

    if (tid < 32) {
        int t = (int)(csum[s_r[tid]] + 0.5f) - 1;
        if (t < 0) t = 0; if (t > 13) t = 13;
        int Wd = 14 - t;
        for (int i = 0; i < 14; i++) {
            int jend = i + Wd - 1; if (jend > 13) jend = 13;
            float a = 0.f;
            for (int j = i; j <= jend; j++) a += s_ch[tid][j];
            s_pool[tid][i] = a / (float)Wd;
        }
    }
    __syncthreads();

    // trans streamed to row-rank position (row-sorted for node_post)
    for (int p = tid; p < 32 * 42; p += 256) {
        int e = p / 42, q = p - e * 42, i = q / 3, d = q - i * 3;
        float diff = x[(size_t)s_r[e] * 42 + q] - poolc[s_c[e] * 3 + d];
        trb[(size_t)s_tp[e] * 42 + q] = F2Bf(diff * s_pool[e][i]);
    }
}

// ---------------- node post: fully streaming aggregation ---------------------
__global__ __launch_bounds__(256, 3) void k_node_post(
    fp h, fp x, const short* __restrict__ wb,
    fp n1B, fp n2B, fp lng, fp lnb,
    const short* __restrict__ efb, const short* __restrict__ trb,
    const int* __restrict__ offc, const int* __restrict__ degc,
    const int* __restrict__ offr, const int* __restrict__ degr,
    float* __restrict__ outh, float* __restrict__ outx) {
    __shared__ __attribute__((aligned(16))) short nA[32 * 264];
    __shared__ __attribute__((aligned(16))) short nMid[32 * 136];
    __shared__ float nY[32][128];
    __shared__ float nred8[32][8];
    __shared__ float nmu[32], nrs[32];

    const int tid = threadIdx.x;
    const int wave = tid >> 6, mt = wave & 1, nh = wave >> 1;
    const int lane = tid & 63, bb = lane & 15, quad = lane >> 4;
    const int nb0 = blockIdx.x * 32;
    const short* n1Wb = wb + 100352;
    const short* n2Wb = wb + 133120;

    // h + streaming agg mean (ef rows contiguous per node)
    for (int p = tid; p < 4096; p += 256) {
        int i = p >> 7, f = p & 127, n = nb0 + i;
        nA[i * 264 + f] = F2Bf(h[(size_t)n * 128 + f]);
        int o0 = offc[n], d = degc[n];
        float s = 0.f;
        int k = 0;
        for (; k + 4 <= d; k += 4) {
            float a0 = B2F(efb[(size_t)(o0 + k) * 128 + f]);
            float a1 = B2F(efb[(size_t)(o0 + k + 1) * 128 + f]);
            float a2 = B2F(efb[(size_t)(o0 + k + 2) * 128 + f]);
            float a3 = B2F(efb[(size_t)(o0 + k + 3) * 128 + f]);
            s += (a0 + a1) + (a2 + a3);
        }
        for (; k < d; k++) s += B2F(efb[(size_t)(o0 + k) * 128 + f]);
        float dd = d > 0 ? (float)d : 1.f;
        nA[i * 264 + 128 + f] = F2Bf(s / dd);
    }
    __syncthreads();

    f32x4 acc[4];
#pragma unroll
    for (int t = 0; t < 4; t++) acc[t] = (f32x4){0.f, 0.f, 0.f, 0.f};
    gemm_lds(nA, 264, n1Wb, 256, 256, mt, nh * 4, 4, acc);
#pragma unroll
    for (int t = 0; t < 4; t++)
#pragma unroll
        for (int i = 0; i < 4; i++) {
            int m = mt * 16 + quad * 4 + i, n = (nh * 4 + t) * 16 + bb;
            nMid[m * 136 + n] = F2Bf(siluf(acc[t][i] + n1B[n]));
        }
    __syncthreads();

#pragma unroll
    for (int t = 0; t < 4; t++) acc[t] = (f32x4){0.f, 0.f, 0.f, 0.f};
    gemm_lds(nMid, 136, n2Wb, 128, 128, mt, nh * 4, 4, acc);
#pragma unroll
    for (int t = 0; t < 4; t++)
#pragma unroll
        for (int i = 0; i < 4; i++) {
            int m = mt * 16 + quad * 4 + i, n = (nh * 4 + t) * 16 + bb;
            nY[m][n] = acc[t][i] + n2B[n] + h[(size_t)(nb0 + m) * 128 + n];
        }
    __syncthreads();

    {
        int i = tid >> 3, j = tid & 7;
        float s = 0.f;
        for (int f = j * 16; f < j * 16 + 16; f++) s += nY[i][f];
        nred8[i][j] = s;
    }
    __syncthreads();
    if (tid < 32) {
        float s = 0.f;
#pragma unroll
        for (int j = 0; j < 8; j++) s += nred8[tid][j];
        nmu[tid] = s * (1.f / 128.f);
    }
    __syncthreads();
    {
        int i = tid >> 3, j = tid & 7;
        float mu = nmu[i], s = 0.f;
        for (int f = j * 16; f < j * 16 + 16; f++) { float d = nY[i][f] - mu; s += d * d; }
        nred8[i][j] = s;
    }
    __syncthreads();
    if (tid < 32) {
        float s = 0.f;
#pragma unroll
        for (int j = 0; j < 8; j++) s += nred8[tid][j];
        nrs[tid] = rsqrtf(s * (1.f / 128.f) + 1e-5f);
    }
    __syncthreads();
    for (int p = tid; p < 32 * 128; p += 256) {
        int i = p >> 7, f = p & 127;
        outh[(size_t)(nb0 + i) * 128 + f] = (nY[i][f] - nmu[i]) * nrs[i] * lng[f] + lnb[f];
    }
    // x_out: trans rows contiguous per node (row-sorted trb)
    for (int p = tid; p < 32 * 42; p += 256) {
        int i = p / 42, q = p - i * 42, n = nb0 + i;
        int o0 = offr[n], d = degr[n];
        float s = 0.f;
        int k = 0;
        for (; k + 4 <= d; k += 4) {
            s += (B2F(trb[(size_t)(o0 + k) * 42 + q]) + B2F(trb[(size_t)(o0 + k + 1) * 42 + q]))
               + (B2F(trb[(size_t)(o0 + k + 2) * 42 + q]) + B2F(trb[(size_t)(o0 + k + 3) * 42 + q]));
        }
        for (; k < d; k++) s += B2F(trb[(size_t)(o0 + k) * 42 + q]);
        float dd = d > 0 ? (float)d : 1.f;
        outx[(size_t)n * 42 + q] = x[(size_t)n * 42 + q] + s / dd;
    }
}

// ---------------- fallback (R8 fused path) -----------------------------------
__global__ __launch_bounds__(256, 3) void k_edge_fused(
    fp x, const int* __restrict__ row, const int* __restrict__ col,
    fp attr, fp cw, const short* __restrict__ hb, const short* __restrict__ wb,
    fp e1B, fp e2B, fp aW, fp aB, fp c1B, fp c2B,
    const float* __restrict__ bc, const float* __restrict__ csum,
    const float* __restrict__ poolc,
    float* __restrict__ xacc, float* __restrict__ agg,
    float* __restrict__ cntr, float* __restrict__ cntc) {
    __shared__ __attribute__((aligned(16))) short R1[13056];
    __shared__ float s_xr2[32 * 42];
    __shared__ float T[4][352];
    __shared__ int   s_r[32], s_c[32];
    __shared__ float s_inv[32];
    __shared__ float s_ch[32][14], s_pool[32][14];
    __shared__ float s_red8[32][8];
    __shared__ float s_gate[32];

    const int tid = threadIdx.x, lane = tid & 63, w = tid >> 6;
    const int bb = lane & 15, quad = lane >> 4;

    if (tid < 32) { s_r[tid] = row[blockIdx.x * 32 + tid]; s_c[tid] = col[blockIdx.x * 32 + tid]; }
    __syncthreads();

    float* slot = T[w];
    float* t2w = slot + 72;
    for (int i8 = 0; i8 < 8; i8++) {
        const int e = w * 8 + i8;
        const int r = s_r[e], cl = s_c[e];
        if (lane < 42) {
            s_xr2[e * 42 + lane] = x[(size_t)r * 42 + lane];
            slot[lane] = x[(size_t)cl * 42 + lane];
        }
        if (lane < 14)      slot[42 + lane] = cw[r * 14 + lane];
        else if (lane < 28) slot[56 + (lane - 14)] = cw[cl * 14 + (lane - 14)];
        __builtin_amdgcn_wave_barrier();

        const int iic = bb < 14 ? bb : 13;
        float xr0 = s_xr2[e * 42 + iic * 3], xr1 = s_xr2[e * 42 + iic * 3 + 1],
              xr2v = s_xr2[e * 42 + iic * 3 + 2];
        float cwri = slot[42 + iic];
        short8 msgv, acv;
#pragma unroll
        for (int t = 0; t < 8; t++) {
            int jj = quad * 8 + t, jc = jj < 14 ? jj : 13;
            float dx = xr0 - slot[jc * 3], dy = xr1 - slot[jc * 3 + 1], dz = xr2v - slot[jc * 3 + 2];
            float m = sqrtf(dx * dx + dy * dy + dz * dz) * cwri * slot[56 + jc];
            msgv[t] = (bb < 14 && jj < 14) ? F2B(m) : (short)0;
            acv[t] = F2B(attr[(size_t)cl * 224 + jc * 16 + bb]);
        }
        f32x4 t2 = (f32x4){0.f, 0.f, 0.f, 0.f};
        t2 = __builtin_amdgcn_mfma_f32_16x16x32_bf16(msgv, acv, t2, 0, 0, 0);
#pragma unroll
        for (int g = 0; g < 4; g++) t2w[(quad * 4 + g) * 17 + bb] = t2[g];
        __builtin_amdgcn_wave_barrier();

        short8 arv, t2v;
#pragma unroll
        for (int t = 0; t < 8; t++) {
            int kk = quad * 8 + t, kc = kk < 16 ? kk : 15;
            t2v[t] = F2B(t2w[kc * 17 + bb]);
            arv[t] = (kk < 14) ? F2B(attr[(size_t)r * 224 + kk * 16 + bb]) : (short)0;
        }
        f32x4 rad = (f32x4){0.f, 0.f, 0.f, 0.f};
        rad = __builtin_amdgcn_mfma_f32_16x16x32_bf16(arv, t2v, rad, 0, 0, 0);

        float ss = rad[0] * rad[0] + rad[1] * rad[1] + rad[2] * rad[2] + rad[3] * rad[3];
#pragma unroll
        for (int off = 32; off > 0; off >>= 1) ss += __shfl_xor(ss, off, 64);
        float inv = 1.f / (sqrtf(ss) + 1.f);
        if (lane == 0) s_inv[e] = inv;
#pragma unroll
        for (int g = 0; g < 4; g++)
            R1[e * 264 + (quad * 4 + g) * 16 + bb] = F2B(rad[g] * inv);
        __builtin_amdgcn_wave_barrier();
    }
    __syncthreads();

    const int mt = w & 1, nh = w >> 1;
    const int m_ = mt * 16 + bb;
    f32x4 acc[4];
#pragma unroll
    for (int t = 0; t < 4; t++) acc[t] = (f32x4){0.f, 0.f, 0.f, 0.f};
    {
        const short* ar_ = hb + (size_t)s_r[m_] * 128 + quad * 8;
        const short* ac_ = hb + (size_t)s_c[m_] * 128 + quad * 8;
        gemm_grow(ar_, wb, 256, 128, nh * 4, 4, acc);
        gemm_grow(ac_, wb + 128, 256, 128, nh * 4, 4, acc);
        gemm_lds(R1, 264, wb + 32768, 256, 256, mt, nh * 4, 4, acc);
    }
    __syncthreads();
    short* V1 = R1;
    short* V2 = R1 + 4352;
    short* C1O = R1 + 8704;
#pragma unroll
    for (int t = 0; t < 4; t++)
#pragma unroll
        for (int i = 0; i < 4; i++) {
            int m = mt * 16 + quad * 4 + i, n = (nh * 4 + t) * 16 + bb;
            V1[m * 136 + n] = F2B(siluf(acc[t][i] + e1B[n] + bc[n] * s_inv[m]));
        }
    __syncthreads();

#pragma unroll
    for (int t = 0; t < 4; t++) acc[t] = (f32x4){0.f, 0.f, 0.f, 0.f};
    gemm_lds(V1, 136, wb + 65536, 128, 128, mt, nh * 4, 4, acc);
    __syncthreads();
#pragma unroll
    for (int t = 0; t < 4; t++)
#pragma unroll
        for (int i = 0; i < 4; i++) {
            int m = mt * 16 + quad * 4 + i, n = (nh * 4 + t) * 16 + bb;
            V2[m * 136 + n] = F2B(siluf(acc[t][i] + e2B[n]));
        }
    __syncthreads();

    {
        int e = tid >> 3, j = tid & 7;
        float s = 0.f;
        for (int f = j * 16; f < j * 16 + 16; f++) s += B2F(V2[e * 136 + f]) * aW[f];
        s_red8[e][j] = s;
    }
    __syncthreads();
    if (tid < 32) {
        float s = 0.f;
#pragma unroll
        for (int j = 0; j < 8; j++) s += s_red8[tid][j];
        s_gate[tid] = 1.f / (1.f + __expf(-(s + aB[0])));
    }
    __syncthreads();
    for (int p = tid; p < 32 * 128; p += 256) {
        int e = p >> 7, f = p & 127;
        V1[e * 136 + f] = F2B(B2F(V2[e * 136 + f]) * s_gate[e]);
    }
    __syncthreads();

#pragma unroll
    for (int t = 0; t < 4; t++) acc[t] = (f32x4){0.f, 0.f, 0.f, 0.f};
    gemm_lds(V1, 136, wb + 81920, 128, 128, mt, nh * 4, 4, acc);
    __syncthreads();
#pragma unroll
    for (int t = 0; t < 4; t++)
#pragma unroll
        for (int i = 0; i < 4; i++) {
            int m = mt * 16 + quad * 4 + i, n = (nh * 4 + t) * 16 + bb;
            C1O[m * 136 + n] = F2B(siluf(acc[t][i] + c1B[n]));
        }
    __syncthreads();

    if (nh == 0) {
        f32x4 a4 = (f32x4){0.f, 0.f, 0.f, 0.f};
        gemm_lds(C1O, 136, wb + 98304, 128, 128, mt, 0, 1, &a4);
#pragma unroll
        for (int i = 0; i < 4; i++) {
            int m = mt * 16 + quad * 4 + i;
            if (bb < 14) s_ch[m][bb] = a4[i] + c2B[bb];
        }
    }
    __syncthreads();

    if (tid < 32) {
        int t = (int)(csum[s_r[tid]] + 0.5f) - 1;
        if (t < 0) t = 0; if (t > 13) t = 13;
        int Wd = 14 - t;
        for (int i = 0; i < 14; i++) {
            int jend = i + Wd - 1; if (jend > 13) jend = 13;
            float a = 0.f;
            for (int j = i; j <= jend; j++) a += s_ch[tid][j];
            s_pool[tid][i] = a / (float)Wd;
        }
    }
    __syncthreads();

    for (int p = tid; p < 32 * 42; p += 256) {
        int e = p / 42, q = p - e * 42, i = q / 3, d = q - i * 3;
        float diff = s_xr2[e * 42 + q] - poolc[s_c[e] * 3 + d];
        atomicAdd(&xacc[(size_t)s_r[e] * 42 + q], diff * s_pool[e][i]);
    }
    for (int p = tid; p < 32 * 128; p += 256) {
        int e = p >> 7, f = p & 127;
        atomicAdd(&agg[(size_t)s_c[e] * 128 + f], B2F(V1[e * 136 + f]));
    }
    if (tid < 32) {
        atomicAdd(&cntr[s_r[tid]], 1.f);
        atomicAdd(&cntc[s_c[tid]], 1.f);
    }
}

__global__ __launch_bounds__(256, 2) void k_node_post_fb(
    fp h, fp x, const short* __restrict__ wb,
    fp n1B, fp n2B, fp lng, fp lnb,
    const float* __restrict__ agg, const float* __restrict__ cntc,
    const float* __restrict__ xacc, const float* __restrict__ cntr,
    float* __restrict__ outh, float* __restrict__ outx) {
    __shared__ __attribute__((aligned(16))) short nA[32 * 264];
    __shared__ __attribute__((aligned(16))) short nMid[32 * 136];
    __shared__ float nY[32][128];
    __shared__ float nred8[32][8];
    __shared__ float nmu[32], nrs[32];

    const int tid = threadIdx.x;
    const int wave = tid >> 6, mt = wave & 1, nh = wave >> 1;
    const int lane = tid & 63, bb = lane & 15, quad = lane >> 4;
    const int nb0 = blockIdx.x * 32;
    const short* n1Wb = wb + 100352;
    const short* n2Wb = wb + 133120;

    for (int p = tid; p < 32 * 128; p += 256) {
        int i = p >> 7, f = p & 127;
        int n = nb0 + i;
        nA[i * 264 + f] = F2Bf(h[(size_t)n * 128 + f]);
        float cc = cntc[n]; if (cc < 1.f) cc = 1.f;
        nA[i * 264 + 128 + f] = F2Bf(agg[(size_t)n * 128 + f] / cc);
    }
    __syncthreads();

    f32x4 acc[4];
#pragma unroll
    for (int t = 0; t < 4; t++) acc[t] = (f32x4){0.f, 0.f, 0.f, 0.f};
    gemm_lds(nA, 264, n1Wb, 256, 256, mt, nh * 4, 4, acc);
#pragma unroll
    for (int t = 0; t < 4; t++)
#pragma unroll
        for (int i = 0; i < 4; i++) {
            int m = mt * 16 + quad * 4 + i, n = (nh * 4 + t) * 16 + bb;
            nMid[m * 136 + n] = F2Bf(siluf(acc[t][i] + n1B[n]));
        }
    __syncthreads();

#pragma unroll
    for (int t = 0; t < 4; t++) acc[t] = (f32x4){0.f, 0.f, 0.f, 0.f};
    gemm_lds(nMid, 136, n2Wb, 128, 128, mt, nh * 4, 4, acc);
#pragma unroll
    for (int t = 0; t < 4; t++)
#pragma unroll
        for (int i = 0; i < 4; i++) {
            int m = mt * 16 + quad * 4 + i, n = (nh * 4 + t) * 16 + bb;
            nY[m][n] = acc[t][i] + n2B[n] + h[(size_t)(nb0 + m) * 128 + n];
        }
    __syncthreads();

    {
        int i = tid >> 3, j = tid & 7;
        float s = 0.f;
        for (int f = j * 16; f < j * 16 + 16; f++) s += nY[i][f];
        nred8[i][j] = s;
    }
    __syncthreads();
    if (tid < 32) {
        float s = 0.f;
#pragma unroll
        for (int j = 0; j < 8; j++) s += nred8[tid][j];
        nmu[tid] = s * (1.f / 128.f);
    }
    __syncthreads();
    {
        int i = tid >> 3, j = tid & 7;
        float mu = nmu[i], s = 0.f;
        for (int f = j * 16; f < j * 16 + 16; f++) { float d = nY[i][f] - mu; s += d * d; }
        nred8[i][j] = s;
    }
    __syncthreads();
    if (tid < 32) {
        float s = 0.f;
#pragma unroll
        for (int j = 0; j < 8; j++) s += nred8[tid][j];
        nrs[tid] = rsqrtf(s * (1.f / 128.f) + 1e-5f);
    }
    __syncthreads();
    for (int p = tid; p < 32 * 128; p += 256) {
        int i = p >> 7, f = p & 127;
        outh[(size_t)(nb0 + i) * 128 + f] = (nY[i][f] - nmu[i]) * nrs[i] * lng[f] + lnb[f];
    }
    for (int p = tid; p < 32 * 42; p += 256) {
        int i = p / 42, q = p - i * 42;
        int n = nb0 + i;
        float cr = cntr[n]; if (cr < 1.f) cr = 1.f;
        outx[(size_t)n * 42 + q] = x[(size_t)n * 42 + q] + xacc[(size_t)n * 42 + q] / cr;
    }
}

extern "C" void kernel_launch(void* const* d_in, const int* in_sizes, int n_in,
                              void* d_out, int out_size, void* d_ws, size_t ws_size,
                              hipStream_t stream) {
    fp h   = (fp)d_in[0];
    fp x   = (fp)d_in[1];
    const int* row = (const int*)d_in[2];
    const int* col = (const int*)d_in[3];
    fp attr= (fp)d_in[4];
    fp cw  = (fp)d_in[5];
    fp rW  = (fp)d_in[6];  fp rB  = (fp)d_in[7];
    fp e1W = (fp)d_in[8];  fp e1B = (fp)d_in[9];
    fp e2W = (fp)d_in[10]; fp e2B = (fp)d_in[11];
    fp aW  = (fp)d_in[12]; fp aB  = (fp)d_in[13];
    fp c1W = (fp)d_in[14]; fp c1B = (fp)d_in[15];
    fp c2W = (fp)d_in[16]; fp c2B = (fp)d_in[17];
    fp n1W = (fp)d_in[18]; fp n1B = (fp)d_in[19];
    fp n2W = (fp)d_in[20]; fp n2B = (fp)d_in[21];
    fp lng = (fp)d_in[22]; fp lnb = (fp)d_in[23];

    // f32-unit offsets:
    // degc 0 | degr 20000 | curc 40000 | curr 60000 | offc 80000 | offr 100008
    // rowp 120016 | colp 440016 | trpos 760016 | csum 1080016 | pool 1100016
    // bc 1160016 | hb 1160144 | wb 2440144 | H12 2514896 | e1p 5074896
    // trb 25554896 | attrT 32274896 | end 34834896  (139.34 MB)
    float* ws    = (float*)d_ws;
    int*   degc  = (int*)ws;
    int*   degr  = (int*)(ws + 20000);
    int*   curc  = (int*)(ws + 40000);
    int*   curr  = (int*)(ws + 60000);
    int*   offc  = (int*)(ws + 80000);
    int*   offr  = (int*)(ws + 100008);
    int*   rowp  = (int*)(ws + 120016);
    int*   colp  = (int*)(ws + 440016);
    int*   trpos = (int*)(ws + 760016);
    float* csum  = ws + 1080016;
    float* pool  = ws + 1100016;
    float* bc    = ws + 1160016;
    short* hb    = (short*)(ws + 1160144);
    short* wb    = (short*)(ws + 2440144);
    short* H12   = (short*)(ws + 2514896);
    short* e1p   = (short*)(ws + 5074896);
    short* trb   = (short*)(ws + 25554896);
    short* attrT = (short*)(ws + 32274896);

    const size_t need = 34834896ull * 4ull;

    if (ws_size >= need) {
        hipMemsetAsync(d_ws, 0, 40000 * sizeof(int), stream);  // degc+degr
        k_prep_w<<<(149504 + 255) / 256, 256, 0, stream>>>(e1W, e2W, c1W, c2W, n1W, n2W, wb);
        k_fold<<<128, 256, 0, stream>>>(e1W, rW, rB, wb, bc);
        k_prep_h<<<(NN * 128 + 255) / 256, 256, 0, stream>>>(h, hb);
        k_node_pre<<<(NN + 255) / 256, 256, 0, stream>>>(x, cw, csum, pool);
        k_prep_attrT<<<(NN * 256 + 255) / 256, 256, 0, stream>>>(attr, attrT);
        k_deg<<<(NE + 255) / 256, 256, 0, stream>>>(row, col, degr, degc);
        k_scan<<<1, 256, 0, stream>>>(degc, degr, offc, offr, curc, curr);
        k_fill<<<(NE + 255) / 256, 256, 0, stream>>>(row, col, curr, curc, rowp, colp, trpos);
        k_hw<<<NN / 32, 256, 0, stream>>>(hb, wb, H12);
        k_radial<<<NE / 64, 256, 0, stream>>>(x, rowp, colp, attrT, cw, wb, bc, e1p);
        k_edge_split<<<NE / 32, 256, 0, stream>>>(x, rowp, colp, trpos, H12, e1p, wb,
                                                  e1B, e2B, aW, aB, c1B, c2B,
                                                  csum, pool, trb);
        float* outh = (float*)d_out;
        float* outx = outh + NN * 128;
        k_node_post<<<NN / 32, 256, 0, stream>>>(h, x, wb, n1B, n2B, lng, lnb,
                                                 e1p, trb,
                                                 offc, degc, offr, degr,
                                                 outh, outx);
    } else {
        float* xacc = ws + 5074896;
        float* agg  = ws + 5914896;
        float* cntr = ws + 8474896;
        float* cntc = ws + 8494896;
        hipMemsetAsync(ws + 5074896, 0, 3440000 * sizeof(float), stream);
        k_prep_w<<<(149504 + 255) / 256, 256, 0, stream>>>(e1W, e2W, c1W, c2W, n1W, n2W, wb);
        k_fold<<<128, 256, 0, stream>>>(e1W, rW, rB, wb, bc);
        k_prep_h<<<(NN * 128 + 255) / 256, 256, 0, stream>>>(h, hb);
        k_node_pre<<<(NN + 255) / 256, 256, 0, stream>>>(x, cw, csum, pool);
        k_edge_fused<<<NE / 32, 256, 0, stream>>>(x, row, col, attr, cw, hb, wb,
                                                  e1B, e2B, aW, aB, c1B, c2B,
                                                  bc, csum, pool, xacc, agg, cntr, cntc);
        float* outh = (float*)d_out;
        float* outx = outh + NN * 128;
        k_node_post_fb<<<NN / 32, 256, 0, stream>>>(h, x, wb, n1B, n2B, lng, lnb,
                                                    agg, cntc, xacc, cntr, outh, outx);
    }
}